// Round 7
// baseline (178.416 us; speedup 1.0000x reference)
//
#include <hip/hip_runtime.h>

#define BB 16
#define CC 768
#define DD 128
#define NN 4096

typedef float f32x4 __attribute__((ext_vector_type(4)));
typedef __bf16 bf16x8 __attribute__((ext_vector_type(8)));
typedef __bf16 bf16x4 __attribute__((ext_vector_type(4)));

__device__ __forceinline__ float wave_reduce_max(float x) {
#pragma unroll
  for (int off = 32; off > 0; off >>= 1) x = fmaxf(x, __shfl_xor(x, off, 64));
  return x;
}
__device__ __forceinline__ float wave_reduce_sum(float x) {
#pragma unroll
  for (int off = 32; off > 0; off >>= 1) x += __shfl_xor(x, off, 64);
  return x;
}

// K1: per (b,d) row: softmax stats over n (max, 1/sum).
// softmax(dt + A[d]) over n == softmax(dt) over n (A constant along axis) -> A unused.
__global__ __launch_bounds__(256) void k_stats(const float* __restrict__ BCdt,
                                               float* __restrict__ stats) {
  int blk = blockIdx.x;  // b*128 + d
  int b = blk >> 7, d = blk & 127;
  const float4* row = (const float4*)(BCdt + ((size_t)b * (2 * DD) + (DD + d)) * NN);
  int t = threadIdx.x;
  float4 v[4];
  float mx = -3.0e38f;
#pragma unroll
  for (int i = 0; i < 4; ++i) {
    v[i] = row[t + 256 * i];
    mx = fmaxf(mx, fmaxf(fmaxf(v[i].x, v[i].y), fmaxf(v[i].z, v[i].w)));
  }
  __shared__ float red[8];
  float wm = wave_reduce_max(mx);
  int wid = t >> 6;
  if ((t & 63) == 0) red[wid] = wm;
  __syncthreads();
  mx = fmaxf(fmaxf(red[0], red[1]), fmaxf(red[2], red[3]));
  float s = 0.f;
#pragma unroll
  for (int i = 0; i < 4; ++i)
    s += __expf(v[i].x - mx) + __expf(v[i].y - mx) + __expf(v[i].z - mx) + __expf(v[i].w - mx);
  float ws = wave_reduce_sum(s);
  if ((t & 63) == 0) red[4 + wid] = ws;
  __syncthreads();
  if (t == 0) {
    float tot = red[4] + red[5] + red[6] + red[7];
    stats[2 * blk] = mx;
    stats[2 * blk + 1] = 1.0f / tot;
  }
}

// K1b: AB = softmax(dt)*BC -> bf16 [b][d][n]; BCt = BC^T -> bf16 [b][n][d].
__global__ __launch_bounds__(256) void k_prep(const float* __restrict__ BCdt,
                                              const float* __restrict__ stats,
                                              __bf16* __restrict__ AB,
                                              __bf16* __restrict__ BCt) {
  int blk = blockIdx.x;  // b*128 + dtile*64 + ntile
  int ntile = blk & 63;
  int dtile = (blk >> 6) & 1;
  int b = blk >> 7;
  int d0 = dtile * 64, n0 = ntile * 64;
  __shared__ __bf16 Ls[64][76];
  int t = threadIdx.x;
  int r = t >> 4;
  int cg = t & 15;
  const float* base = BCdt + (size_t)b * (2 * DD) * NN;
#pragma unroll
  for (int p = 0; p < 4; ++p) {
    int dl = r + p * 16;
    int d = d0 + dl;
    float4 bc = *(const float4*)(base + (size_t)d * NN + n0 + cg * 4);
    float4 dt = *(const float4*)(base + (size_t)(DD + d) * NN + n0 + cg * 4);
    float mx = stats[2 * (b * DD + d)];
    float inv = stats[2 * (b * DD + d) + 1];
    bf16x4 abv;
    abv[0] = (__bf16)(__expf(dt.x - mx) * inv * bc.x);
    abv[1] = (__bf16)(__expf(dt.y - mx) * inv * bc.y);
    abv[2] = (__bf16)(__expf(dt.z - mx) * inv * bc.z);
    abv[3] = (__bf16)(__expf(dt.w - mx) * inv * bc.w);
    *(bf16x4*)(AB + ((size_t)(b * DD + d)) * NN + n0 + cg * 4) = abv;
    bf16x4 bcv;
    bcv[0] = (__bf16)bc.x; bcv[1] = (__bf16)bc.y; bcv[2] = (__bf16)bc.z; bcv[3] = (__bf16)bc.w;
    *(bf16x4*)(&Ls[dl][cg * 4]) = bcv;
  }
  __syncthreads();
#pragma unroll
  for (int p = 0; p < 4; ++p) {
    int j = r + p * 16;
    bf16x4 v;
#pragma unroll
    for (int k = 0; k < 4; ++k) v[k] = Ls[cg * 4 + k][j];
    *(bf16x4*)(BCt + ((size_t)b * NN + n0 + j) * DD + d0 + cg * 4) = v;
  }
}

// K2: partial hmat: hpart[q][b][c][d] = sum_{n in slab q} x[b][c][n]*AB[b][d][n].
// 128x128 tile, split-K x8. DEPTH-2 register prefetch: tile s+2's global loads
// are issued at iter s (>=2 staging+MFMA phases before their consumer at iter
// s+2's cvt) so ~900cy HBM latency is covered and the memory pipe never idles.
// The per-iter "memory"-clobber asm fence pins issue order. One raw s_barrier
// per iter (lgkmcnt only -- global loads stay in flight across it).
// AB B-frags direct from global (L2-hot).
__global__ __launch_bounds__(256) void k_hmat(const float* __restrict__ x,
                                              const __bf16* __restrict__ AB,
                                              __bf16* __restrict__ hpart) {
  int blk = blockIdx.x;  // ((b*6 + mt)<<3) | q
  int q = blk & 7;
  int rest = blk >> 3;
  int mt = rest % 6;
  int b = rest / 6;
  int c0 = mt * 128;
  int kbase = q * 512;
  __shared__ __bf16 Xs[2][128][72];  // 36864 B; [72] pad -> 2-way (free) frag reads
  __bf16(*Ls16)[136] = (__bf16(*)[136])&Xs[0][0][0];  // epilogue restage (17408 B)
  int t = threadIdx.x;
  int lane = t & 63, w = t >> 6;
  int wr = w >> 1, wc = w & 1;
  int fr = lane & 15, fg = lane >> 4;
  int rs = t >> 3, c8 = t & 7;  // staging: 32 rows x 8 col-chunks (8 floats)
  f32x4 acc[4][4] = {};
  const float* xsrc = x + ((size_t)b * CC + c0) * NN + kbase;
  const __bf16* abb = AB + ((size_t)b * DD + wc * 64 + fr) * NN + kbase + fg * 8;
  float4 R0a[4], R0b[4], R1a[4], R1b[4];  // two prefetch buffers (ping-pong)
#define ISSUE(s, RA, RB)                                               \
  {                                                                    \
    _Pragma("unroll") for (int p = 0; p < 4; ++p) {                    \
      const float* pp = xsrc + (size_t)(p * 32 + rs) * NN + (s) * 64 + c8 * 8; \
      RA[p] = *(const float4*)pp;                                      \
      RB[p] = *(const float4*)(pp + 4);                                \
    }                                                                  \
  }
  ISSUE(0, R0a, R0b);
  ISSUE(1, R1a, R1b);
#pragma unroll
  for (int s = 0; s < 8; ++s) {
#pragma unroll
    for (int p = 0; p < 4; ++p) {  // cvt + 16B ds_write of tile s
      bf16x8 v;
      if ((s & 1) == 0) {
        v[0] = (__bf16)R0a[p].x; v[1] = (__bf16)R0a[p].y;
        v[2] = (__bf16)R0a[p].z; v[3] = (__bf16)R0a[p].w;
        v[4] = (__bf16)R0b[p].x; v[5] = (__bf16)R0b[p].y;
        v[6] = (__bf16)R0b[p].z; v[7] = (__bf16)R0b[p].w;
      } else {
        v[0] = (__bf16)R1a[p].x; v[1] = (__bf16)R1a[p].y;
        v[2] = (__bf16)R1a[p].z; v[3] = (__bf16)R1a[p].w;
        v[4] = (__bf16)R1b[p].x; v[5] = (__bf16)R1b[p].y;
        v[6] = (__bf16)R1b[p].z; v[7] = (__bf16)R1b[p].w;
      }
      *(bf16x8*)(&Xs[s & 1][p * 32 + rs][c8 * 8]) = v;
    }
    if (s < 6) {  // refill the buffer just drained with tile s+2
      if ((s & 1) == 0) { ISSUE(s + 2, R0a, R0b); }
      else              { ISSUE(s + 2, R1a, R1b); }
    }
    asm volatile("s_waitcnt lgkmcnt(0)" ::: "memory");
    __builtin_amdgcn_s_barrier();  // do NOT drain vmcnt (prefetch stays in flight)
#pragma unroll
    for (int kk = 0; kk < 2; ++kk) {
      bf16x8 a[4], bfr[4];
#pragma unroll
      for (int i = 0; i < 4; ++i)
        a[i] = *(const bf16x8*)(&Xs[s & 1][wr * 64 + i * 16 + fr][kk * 32 + fg * 8]);
#pragma unroll
      for (int i = 0; i < 4; ++i)
        bfr[i] = *(const bf16x8*)(abb + (size_t)(i * 16) * NN + s * 64 + kk * 32);
#pragma unroll
      for (int mi = 0; mi < 4; ++mi)
#pragma unroll
        for (int ni = 0; ni < 4; ++ni)
          acc[mi][ni] = __builtin_amdgcn_mfma_f32_16x16x32_bf16(a[mi], bfr[ni], acc[mi][ni], 0, 0, 0);
    }
  }
#undef ISSUE
  // Epilogue: bf16 partial tile, LDS restage in two 64-row halves, 16B stores.
  __bf16* hp = hpart + (((size_t)q * BB + b) * CC + c0) * DD;
#pragma unroll
  for (int half = 0; half < 2; ++half) {
    __syncthreads();
    if (wr == half) {
#pragma unroll
      for (int mi = 0; mi < 4; ++mi)
#pragma unroll
        for (int ni = 0; ni < 4; ++ni)
#pragma unroll
          for (int ri = 0; ri < 4; ++ri)
            Ls16[mi * 16 + fg * 4 + ri][wc * 64 + ni * 16 + fr] = (__bf16)acc[mi][ni][ri];
    }
    __syncthreads();
#pragma unroll
    for (int j = 0; j < 4; ++j) {
      int chunk = j * 256 + t;  // 1024 chunks = 64 rows x 16 x (8 bf16)
      int row = chunk >> 4, col8 = chunk & 15;
      bf16x8 v = *(const bf16x8*)(&Ls16[row][col8 * 8]);
      *(bf16x8*)(hp + (size_t)(half * 64 + row) * DD + col8 * 8) = v;
    }
  }
}

// K2b: hmatB = sum_q hpart[q] (fp32 accum) -> bf16.
__global__ __launch_bounds__(256) void k_conv(const __bf16* __restrict__ hpart,
                                              __bf16* __restrict__ hmatB) {
  size_t idx = (size_t)blockIdx.x * 2048 + (size_t)threadIdx.x * 8;
  const size_t stride = (size_t)BB * CC * DD;
  float s[8] = {};
#pragma unroll
  for (int q = 0; q < 8; ++q) {
    bf16x8 v = *(const bf16x8*)(hpart + q * stride + idx);
#pragma unroll
    for (int j = 0; j < 8; ++j) s[j] += (float)v[j];
  }
  bf16x8 o;
#pragma unroll
  for (int j = 0; j < 8; ++j) o[j] = (__bf16)s[j];
  *(bf16x8*)(hmatB + idx) = o;
}

// K3: y[b][c][n] = sum_d hmatB[b][c][d]*BCt[b][n][d]; 128c x 128n tile, K=128.
// Inputs cache-resident -> fragments direct from global; output restaged via LDS.
__global__ __launch_bounds__(256, 4) void k_y(const __bf16* __restrict__ hmatB,
                                              const __bf16* __restrict__ BCt,
                                              float* __restrict__ y) {
  int blk = blockIdx.x;  // ((b*6+mt)<<5) | nt
  int nt = blk & 31;
  int rest = blk >> 5;
  int mt = rest % 6;
  int b = rest / 6;
  int c0 = mt * 128, n0 = nt * 128;
  __shared__ float St[64][132];
  int t = threadIdx.x;
  int lane = t & 63, w = t >> 6;
  int wr = w >> 1, wc = w & 1;
  int fr = lane & 15, fg = lane >> 4;
  const __bf16* hb = hmatB + ((size_t)b * CC + c0 + wr * 64 + fr) * DD;
  const __bf16* bb = BCt + ((size_t)b * NN + n0 + wc * 64 + fr) * DD;
  f32x4 acc[4][4] = {};
#pragma unroll
  for (int kk = 0; kk < 4; ++kk) {
    bf16x8 a[4], bfr[4];
#pragma unroll
    for (int i = 0; i < 4; ++i)
      a[i] = *(const bf16x8*)(hb + (size_t)(i * 16) * DD + kk * 32 + fg * 8);
#pragma unroll
    for (int i = 0; i < 4; ++i)
      bfr[i] = *(const bf16x8*)(bb + (size_t)(i * 16) * DD + kk * 32 + fg * 8);
#pragma unroll
    for (int mi = 0; mi < 4; ++mi)
#pragma unroll
      for (int ni = 0; ni < 4; ++ni)
        acc[mi][ni] = __builtin_amdgcn_mfma_f32_16x16x32_bf16(a[mi], bfr[ni], acc[mi][ni], 0, 0, 0);
  }
  float* yb = y + ((size_t)b * CC + c0) * NN + n0;
  int rr3 = t >> 5, cg3 = t & 31;
#pragma unroll
  for (int half = 0; half < 2; ++half) {
    if (wr == half) {
#pragma unroll
      for (int mi = 0; mi < 4; ++mi)
#pragma unroll
        for (int ni = 0; ni < 4; ++ni)
#pragma unroll
          for (int ri = 0; ri < 4; ++ri)
            St[mi * 16 + fg * 4 + ri][wc * 64 + ni * 16 + fr] = acc[mi][ni][ri];
    }
    __syncthreads();
#pragma unroll
    for (int p = 0; p < 8; ++p) {
      int lrow = rr3 + p * 8;
      float4 v = *(const float4*)(&St[lrow][cg3 * 4]);
      *(float4*)(yb + (size_t)(half * 64 + lrow) * NN + cg3 * 4) = v;
    }
    __syncthreads();
  }
}

extern "C" void kernel_launch(void* const* d_in, const int* in_sizes, int n_in,
                              void* d_out, int out_size, void* d_ws, size_t ws_size,
                              hipStream_t stream) {
  (void)in_sizes; (void)n_in; (void)out_size; (void)ws_size;
  const float* BCdt = (const float*)d_in[0];
  const float* x = (const float*)d_in[1];
  // d_in[2] (A) unused: softmax shift-invariance.
  char* ws = (char*)d_ws;
  size_t offAB = 0;
  size_t offBCt = offAB + (size_t)BB * DD * NN * 2;   // 16.78 MB
  size_t offHB = offBCt + (size_t)BB * NN * DD * 2;   // +16.78 MB
  size_t offS = offHB + (size_t)BB * CC * DD * 2;     // +3.15 MB
  __bf16* AB = (__bf16*)(ws + offAB);
  __bf16* BCt = (__bf16*)(ws + offBCt);
  __bf16* hmatB = (__bf16*)(ws + offHB);
  float* stats = (float*)(ws + offS);
  // Partial sums live in d_out (25.2 MB of 201 MB); k_y overwrites d_out last.
  __bf16* hpart = (__bf16*)d_out;
  float* y = (float*)d_out;

  k_stats<<<dim3(BB * DD), dim3(256), 0, stream>>>(BCdt, stats);
  k_prep<<<dim3(BB * 2 * 64), dim3(256), 0, stream>>>(BCdt, stats, AB, BCt);
  k_hmat<<<dim3(BB * 6 * 8), dim3(256), 0, stream>>>(x, AB, hpart);
  k_conv<<<dim3(768), dim3(256), 0, stream>>>(hpart, hmatB);
  k_y<<<dim3(BB * 6 * 32), dim3(256), 0, stream>>>(hmatB, BCt, y);
}

// Round 8
// 166.898 us; speedup vs baseline: 1.0690x; 1.0690x over previous
//
#include <hip/hip_runtime.h>

#define BB 16
#define CC 768
#define DD 128
#define NN 4096

typedef float f32x4 __attribute__((ext_vector_type(4)));
typedef __bf16 bf16x8 __attribute__((ext_vector_type(8)));
typedef __bf16 bf16x4 __attribute__((ext_vector_type(4)));

__device__ __forceinline__ float wave_reduce_max(float x) {
#pragma unroll
  for (int off = 32; off > 0; off >>= 1) x = fmaxf(x, __shfl_xor(x, off, 64));
  return x;
}
__device__ __forceinline__ float wave_reduce_sum(float x) {
#pragma unroll
  for (int off = 32; off > 0; off >>= 1) x += __shfl_xor(x, off, 64);
  return x;
}

// K1: per (b,d) row: softmax stats over n (max, 1/sum).
// softmax(dt + A[d]) over n == softmax(dt) over n (A constant along axis) -> A unused.
__global__ __launch_bounds__(256) void k_stats(const float* __restrict__ BCdt,
                                               float* __restrict__ stats) {
  int blk = blockIdx.x;  // b*128 + d
  int b = blk >> 7, d = blk & 127;
  const float4* row = (const float4*)(BCdt + ((size_t)b * (2 * DD) + (DD + d)) * NN);
  int t = threadIdx.x;
  float4 v[4];
  float mx = -3.0e38f;
#pragma unroll
  for (int i = 0; i < 4; ++i) {
    v[i] = row[t + 256 * i];
    mx = fmaxf(mx, fmaxf(fmaxf(v[i].x, v[i].y), fmaxf(v[i].z, v[i].w)));
  }
  __shared__ float red[8];
  float wm = wave_reduce_max(mx);
  int wid = t >> 6;
  if ((t & 63) == 0) red[wid] = wm;
  __syncthreads();
  mx = fmaxf(fmaxf(red[0], red[1]), fmaxf(red[2], red[3]));
  float s = 0.f;
#pragma unroll
  for (int i = 0; i < 4; ++i)
    s += __expf(v[i].x - mx) + __expf(v[i].y - mx) + __expf(v[i].z - mx) + __expf(v[i].w - mx);
  float ws = wave_reduce_sum(s);
  if ((t & 63) == 0) red[4 + wid] = ws;
  __syncthreads();
  if (t == 0) {
    float tot = red[4] + red[5] + red[6] + red[7];
    stats[2 * blk] = mx;
    stats[2 * blk + 1] = 1.0f / tot;
  }
}

// K1b: AB = softmax(dt)*BC -> bf16 [b][d][n]; BCt = BC^T -> bf16 [b][n][d].
__global__ __launch_bounds__(256) void k_prep(const float* __restrict__ BCdt,
                                              const float* __restrict__ stats,
                                              __bf16* __restrict__ AB,
                                              __bf16* __restrict__ BCt) {
  int blk = blockIdx.x;  // b*128 + dtile*64 + ntile
  int ntile = blk & 63;
  int dtile = (blk >> 6) & 1;
  int b = blk >> 7;
  int d0 = dtile * 64, n0 = ntile * 64;
  __shared__ __bf16 Ls[64][76];
  int t = threadIdx.x;
  int r = t >> 4;
  int cg = t & 15;
  const float* base = BCdt + (size_t)b * (2 * DD) * NN;
#pragma unroll
  for (int p = 0; p < 4; ++p) {
    int dl = r + p * 16;
    int d = d0 + dl;
    float4 bc = *(const float4*)(base + (size_t)d * NN + n0 + cg * 4);
    float4 dt = *(const float4*)(base + (size_t)(DD + d) * NN + n0 + cg * 4);
    float mx = stats[2 * (b * DD + d)];
    float inv = stats[2 * (b * DD + d) + 1];
    bf16x4 abv;
    abv[0] = (__bf16)(__expf(dt.x - mx) * inv * bc.x);
    abv[1] = (__bf16)(__expf(dt.y - mx) * inv * bc.y);
    abv[2] = (__bf16)(__expf(dt.z - mx) * inv * bc.z);
    abv[3] = (__bf16)(__expf(dt.w - mx) * inv * bc.w);
    *(bf16x4*)(AB + ((size_t)(b * DD + d)) * NN + n0 + cg * 4) = abv;
    bf16x4 bcv;
    bcv[0] = (__bf16)bc.x; bcv[1] = (__bf16)bc.y; bcv[2] = (__bf16)bc.z; bcv[3] = (__bf16)bc.w;
    *(bf16x4*)(&Ls[dl][cg * 4]) = bcv;
  }
  __syncthreads();
#pragma unroll
  for (int p = 0; p < 4; ++p) {
    int j = r + p * 16;
    bf16x4 v;
#pragma unroll
    for (int k = 0; k < 4; ++k) v[k] = Ls[cg * 4 + k][j];
    *(bf16x4*)(BCt + ((size_t)b * NN + n0 + j) * DD + d0 + cg * 4) = v;
  }
}

// K2: partial hmat: hpart[q][b][c][d] = sum_{n in slab q} x[b][c][n]*AB[b][d][n].
// 128x128 tile, split-K x8. x staged fp32 DIRECT-TO-LDS via global_load_lds
// (async DMA, no VGPR round-trip), double-buffered, counted vmcnt(8) across
// raw s_barriers (the m97/m201 pattern -- the load queue is never drained to 0
// inside the loop). bf16 convert happens at ds_read time (hides under MFMA).
// LDS layout [128][64] f32 with 4-bit XOR chunk swizzle (chunk ^= row&15),
// applied BOTH sides (rule #21): linear DMA dest + pre-swizzled per-lane
// GLOBAL source + swizzled ds_read address. Each 16-lane group still reads a
// contiguous 256B row segment -> fully coalesced. AB B-frags direct (L2-hot).
__global__ __launch_bounds__(256) void k_hmat(const float* __restrict__ x,
                                              const __bf16* __restrict__ AB,
                                              __bf16* __restrict__ hpart) {
  int blk = blockIdx.x;  // ((b*6 + mt)<<3) | q
  int q = blk & 7;
  int rest = blk >> 3;
  int mt = rest % 6;
  int b = rest / 6;
  int c0 = mt * 128;
  int kbase = q * 512;
  __shared__ __align__(16) char smem[65536];   // 2 x 32KB fp32 tile buffers
  __bf16(*Ls16)[136] = (__bf16(*)[136])smem;   // epilogue alias (17408B)
  int t = threadIdx.x;
  int lane = t & 63, w = t >> 6;
  int wr = w >> 1, wc = w & 1;
  int fr = lane & 15, fg = lane >> 4;
  f32x4 acc[4][4] = {};
  // staging geometry: dest (linear, forced) byte = i*4096 + t*16
  //   -> row = i*16 + (t>>4), stored chunk = t&15
  //   logical chunk there = (t&15) ^ (row&15) = (t&15) ^ (t>>4)
  int srow = t >> 4;                 // 0..15
  int schunk = (t & 15) ^ srow;      // pre-swizzled source chunk (fixed per thread)
  const float* xsrc = x + ((size_t)b * CC + c0) * NN + kbase;
  const float* xlane = xsrc + (size_t)srow * NN + schunk * 4;
  const __bf16* abb = AB + ((size_t)b * DD + wc * 64 + fr) * NN + kbase + fg * 8;

#define ISSUE(s, bsel)                                                        \
  {                                                                           \
    _Pragma("unroll") for (int i = 0; i < 8; ++i) {                           \
      const float* g = xlane + (size_t)(i * 16) * NN + (s) * 64;              \
      char* l = smem + (bsel) * 32768 + i * 4096 + w * 1024;                  \
      __builtin_amdgcn_global_load_lds(                                       \
          (const __attribute__((address_space(1))) char*)g,                   \
          (__attribute__((address_space(3))) char*)l, 16, 0, 0);              \
    }                                                                         \
  }

  ISSUE(0, 0);
  ISSUE(1, 1);
  asm volatile("s_waitcnt vmcnt(8)" ::: "memory");  // tile 0 (mine) landed
  __builtin_amdgcn_s_barrier();                     // tile 0 (everyone) landed
#pragma unroll
  for (int s = 0; s < 8; ++s) {
    const char* bufc = smem + (s & 1) * 32768;
#pragma unroll
    for (int kk = 0; kk < 2; ++kk) {
      bf16x8 a[4], bfr[4];
#pragma unroll
      for (int i = 0; i < 4; ++i) {
        int row = wr * 64 + i * 16 + fr;       // row&15 == fr
        int ch = kk * 8 + fg * 2;
        f32x4 f0 = *(const f32x4*)(bufc + row * 256 + ((ch) ^ fr) * 16);
        f32x4 f1 = *(const f32x4*)(bufc + row * 256 + ((ch + 1) ^ fr) * 16);
        a[i][0] = (__bf16)f0[0]; a[i][1] = (__bf16)f0[1];
        a[i][2] = (__bf16)f0[2]; a[i][3] = (__bf16)f0[3];
        a[i][4] = (__bf16)f1[0]; a[i][5] = (__bf16)f1[1];
        a[i][6] = (__bf16)f1[2]; a[i][7] = (__bf16)f1[3];
      }
#pragma unroll
      for (int i = 0; i < 4; ++i)
        bfr[i] = *(const bf16x8*)(abb + (size_t)(i * 16) * NN + s * 64 + kk * 32);
#pragma unroll
      for (int mi = 0; mi < 4; ++mi)
#pragma unroll
        for (int ni = 0; ni < 4; ++ni)
          acc[mi][ni] = __builtin_amdgcn_mfma_f32_16x16x32_bf16(a[mi], bfr[ni], acc[mi][ni], 0, 0, 0);
    }
    __builtin_amdgcn_s_barrier();  // all waves done reading buf[s&1]
    if (s < 6) {
      ISSUE(s + 2, s & 1);         // refill the buffer just released
      asm volatile("s_waitcnt vmcnt(8)" ::: "memory");  // tile s+1 landed
    } else if (s == 6) {
      asm volatile("s_waitcnt vmcnt(0)" ::: "memory");  // tail: tile 7 landed
    }
    __builtin_amdgcn_s_barrier();  // everyone's next tile confirmed
  }
#undef ISSUE
  // Epilogue: bf16 partial tile, LDS restage in two 64-row halves, 16B stores.
  __bf16* hp = hpart + (((size_t)q * BB + b) * CC + c0) * DD;
#pragma unroll
  for (int half = 0; half < 2; ++half) {
    __syncthreads();
    if (wr == half) {
#pragma unroll
      for (int mi = 0; mi < 4; ++mi)
#pragma unroll
        for (int ni = 0; ni < 4; ++ni)
#pragma unroll
          for (int ri = 0; ri < 4; ++ri)
            Ls16[mi * 16 + fg * 4 + ri][wc * 64 + ni * 16 + fr] = (__bf16)acc[mi][ni][ri];
    }
    __syncthreads();
#pragma unroll
    for (int j = 0; j < 4; ++j) {
      int chunk = j * 256 + t;  // 1024 chunks = 64 rows x 16 x (8 bf16)
      int row = chunk >> 4, col8 = chunk & 15;
      bf16x8 v = *(const bf16x8*)(&Ls16[row][col8 * 8]);
      *(bf16x8*)(hp + (size_t)(half * 64 + row) * DD + col8 * 8) = v;
    }
  }
}

// K2b: hmatB = sum_q hpart[q] (fp32 accum) -> bf16.
__global__ __launch_bounds__(256) void k_conv(const __bf16* __restrict__ hpart,
                                              __bf16* __restrict__ hmatB) {
  size_t idx = (size_t)blockIdx.x * 2048 + (size_t)threadIdx.x * 8;
  const size_t stride = (size_t)BB * CC * DD;
  float s[8] = {};
#pragma unroll
  for (int q = 0; q < 8; ++q) {
    bf16x8 v = *(const bf16x8*)(hpart + q * stride + idx);
#pragma unroll
    for (int j = 0; j < 8; ++j) s[j] += (float)v[j];
  }
  bf16x8 o;
#pragma unroll
  for (int j = 0; j < 8; ++j) o[j] = (__bf16)s[j];
  *(bf16x8*)(hmatB + idx) = o;
}

// K3: y[b][c][n] = sum_d hmatB[b][c][d]*BCt[b][n][d]; 128c x 128n tile, K=128.
// Inputs cache-resident -> fragments direct from global; output restaged via LDS.
__global__ __launch_bounds__(256, 4) void k_y(const __bf16* __restrict__ hmatB,
                                              const __bf16* __restrict__ BCt,
                                              float* __restrict__ y) {
  int blk = blockIdx.x;  // ((b*6+mt)<<5) | nt
  int nt = blk & 31;
  int rest = blk >> 5;
  int mt = rest % 6;
  int b = rest / 6;
  int c0 = mt * 128, n0 = nt * 128;
  __shared__ float St[64][132];
  int t = threadIdx.x;
  int lane = t & 63, w = t >> 6;
  int wr = w >> 1, wc = w & 1;
  int fr = lane & 15, fg = lane >> 4;
  const __bf16* hb = hmatB + ((size_t)b * CC + c0 + wr * 64 + fr) * DD;
  const __bf16* bb = BCt + ((size_t)b * NN + n0 + wc * 64 + fr) * DD;
  f32x4 acc[4][4] = {};
#pragma unroll
  for (int kk = 0; kk < 4; ++kk) {
    bf16x8 a[4], bfr[4];
#pragma unroll
    for (int i = 0; i < 4; ++i)
      a[i] = *(const bf16x8*)(hb + (size_t)(i * 16) * DD + kk * 32 + fg * 8);
#pragma unroll
    for (int i = 0; i < 4; ++i)
      bfr[i] = *(const bf16x8*)(bb + (size_t)(i * 16) * DD + kk * 32 + fg * 8);
#pragma unroll
    for (int mi = 0; mi < 4; ++mi)
#pragma unroll
      for (int ni = 0; ni < 4; ++ni)
        acc[mi][ni] = __builtin_amdgcn_mfma_f32_16x16x32_bf16(a[mi], bfr[ni], acc[mi][ni], 0, 0, 0);
  }
  float* yb = y + ((size_t)b * CC + c0) * NN + n0;
  int rr3 = t >> 5, cg3 = t & 31;
#pragma unroll
  for (int half = 0; half < 2; ++half) {
    if (wr == half) {
#pragma unroll
      for (int mi = 0; mi < 4; ++mi)
#pragma unroll
        for (int ni = 0; ni < 4; ++ni)
#pragma unroll
          for (int ri = 0; ri < 4; ++ri)
            St[mi * 16 + fg * 4 + ri][wc * 64 + ni * 16 + fr] = acc[mi][ni][ri];
    }
    __syncthreads();
#pragma unroll
    for (int p = 0; p < 8; ++p) {
      int lrow = rr3 + p * 8;
      float4 v = *(const float4*)(&St[lrow][cg3 * 4]);
      *(float4*)(yb + (size_t)(half * 64 + lrow) * NN + cg3 * 4) = v;
    }
    __syncthreads();
  }
}

extern "C" void kernel_launch(void* const* d_in, const int* in_sizes, int n_in,
                              void* d_out, int out_size, void* d_ws, size_t ws_size,
                              hipStream_t stream) {
  (void)in_sizes; (void)n_in; (void)out_size; (void)ws_size;
  const float* BCdt = (const float*)d_in[0];
  const float* x = (const float*)d_in[1];
  // d_in[2] (A) unused: softmax shift-invariance.
  char* ws = (char*)d_ws;
  size_t offAB = 0;
  size_t offBCt = offAB + (size_t)BB * DD * NN * 2;   // 16.78 MB
  size_t offHB = offBCt + (size_t)BB * NN * DD * 2;   // +16.78 MB
  size_t offS = offHB + (size_t)BB * CC * DD * 2;     // +3.15 MB
  __bf16* AB = (__bf16*)(ws + offAB);
  __bf16* BCt = (__bf16*)(ws + offBCt);
  __bf16* hmatB = (__bf16*)(ws + offHB);
  float* stats = (float*)(ws + offS);
  // Partial sums live in d_out (25.2 MB of 201 MB); k_y overwrites d_out last.
  __bf16* hpart = (__bf16*)d_out;
  float* y = (float*)d_out;

  k_stats<<<dim3(BB * DD), dim3(256), 0, stream>>>(BCdt, stats);
  k_prep<<<dim3(BB * 2 * 64), dim3(256), 0, stream>>>(BCdt, stats, AB, BCt);
  k_hmat<<<dim3(BB * 6 * 8), dim3(256), 0, stream>>>(x, AB, hpart);
  k_conv<<<dim3(768), dim3(256), 0, stream>>>(hpart, hmatB);
  k_y<<<dim3(BB * 6 * 32), dim3(256), 0, stream>>>(hmatB, BCt, y);
}